// Round 17
// baseline (233.023 us; speedup 1.0000x reference)
//
#include <hip/hip_runtime.h>
#include <hip/hip_bf16.h>

typedef __attribute__((ext_vector_type(8))) short short8;
typedef __attribute__((ext_vector_type(4))) float f32x4;
typedef __attribute__((ext_vector_type(2))) float f32x2;

#define EPS 1e-5f

__device__ __forceinline__ unsigned short f2bf(float f) {
    union { float f; unsigned u; } v; v.f = f;
    unsigned u = v.u;
    u += 0x7FFFu + ((u >> 16) & 1u);   // RNE
    return (unsigned short)(u >> 16);
}
__device__ __forceinline__ float bflo(unsigned u) {
    union { unsigned u; float f; } v; v.u = u << 16; return v.f;
}
__device__ __forceinline__ float bfhi(unsigned u) {
    union { unsigned u; float f; } v; v.u = u & 0xffff0000u; return v.f;
}
__device__ __forceinline__ float bf2f(ushort u) {
    union { unsigned u; float f; } v; v.u = ((unsigned)u) << 16; return v.f;
}
__device__ __forceinline__ unsigned char f2fp8(float v) {
    return (unsigned char)(__builtin_amdgcn_cvt_pk_fp8_f32(v, v, 0, false) & 0xff);
}
__device__ __forceinline__ unsigned pk4fp8(float a, float b, float c, float d) {
    unsigned u = __builtin_amdgcn_cvt_pk_fp8_f32(a, b, 0, false);
    u = __builtin_amdgcn_cvt_pk_fp8_f32(c, d, u, true);
    return u;
}
__device__ __forceinline__ int sig(int p) {            // sigma: acc-layout k-permutation
    return (((p >> 2) & 1) << 4) | (((p >> 3) & 3) << 2) | (p & 3);
}

// load 8 consecutive f32, convert to a bf16x8 MFMA fragment
__device__ __forceinline__ short8 load_frag_f32(const float* __restrict__ p) {
    f32x4 a = *(const f32x4*)p;
    f32x4 b = *(const f32x4*)(p + 4);
    short8 r;
    r[0] = (short)f2bf(a[0]); r[1] = (short)f2bf(a[1]);
    r[2] = (short)f2bf(a[2]); r[3] = (short)f2bf(a[3]);
    r[4] = (short)f2bf(b[0]); r[5] = (short)f2bf(b[1]);
    r[6] = (short)f2bf(b[2]); r[7] = (short)f2bf(b[3]);
    return r;
}

// dot(q[0..16) bf16, k[0..16) fp8) for one head
__device__ __forceinline__ float dot16_q_k8(const ushort* q, const unsigned char* kp) {
    uint4 kw = *(const uint4*)kp;
    const unsigned* qd = (const unsigned*)q;
    f32x2 a, b; float s = 0.f;
    a = __builtin_amdgcn_cvt_pk_f32_fp8(kw.x, false);
    b = __builtin_amdgcn_cvt_pk_f32_fp8(kw.x, true);
    s += a[0]*bflo(qd[0]) + a[1]*bfhi(qd[0]) + b[0]*bflo(qd[1]) + b[1]*bfhi(qd[1]);
    a = __builtin_amdgcn_cvt_pk_f32_fp8(kw.y, false);
    b = __builtin_amdgcn_cvt_pk_f32_fp8(kw.y, true);
    s += a[0]*bflo(qd[2]) + a[1]*bfhi(qd[2]) + b[0]*bflo(qd[3]) + b[1]*bfhi(qd[3]);
    a = __builtin_amdgcn_cvt_pk_f32_fp8(kw.z, false);
    b = __builtin_amdgcn_cvt_pk_f32_fp8(kw.z, true);
    s += a[0]*bflo(qd[4]) + a[1]*bfhi(qd[4]) + b[0]*bflo(qd[5]) + b[1]*bfhi(qd[5]);
    a = __builtin_amdgcn_cvt_pk_f32_fp8(kw.w, false);
    b = __builtin_amdgcn_cvt_pk_f32_fp8(kw.w, true);
    s += a[0]*bflo(qd[6]) + a[1]*bfhi(qd[6]) + b[0]*bflo(qd[7]) + b[1]*bfhi(qd[7]);
    return s;
}

// ---------------- K0: weight transforms (unchanged layout) ------------------
__global__ __launch_bounds__(256) void k_prep(
        const float* __restrict__ ipw, const float* __restrict__ ow,
        const float* __restrict__ w1, const float* __restrict__ w2,
        ushort* __restrict__ wqb, unsigned char* __restrict__ wcat8) {
    int i = blockIdx.x * 256 + threadIdx.x;
    if (i < 49152) wqb[i] = f2bf(ipw[i]);
    if (i < 147456) {
        float v;
        if (i < 16384) {
            int r = i >> 7, s = (i >> 3) & 15, e = i & 7;
            v = ow[r*128 + ((s ^ (r & 15)) << 3) + e];
        } else if (i < 81920) {
            int j = i - 16384;
            int kb = j >> 12, r = (j >> 7) & 31, s = (j >> 3) & 15, e = j & 7;
            int cp = ((s ^ (r & 15)) << 3) + e;
            int cs = (cp & ~31) | sig(cp & 31);
            v = w1[(kb*32 + r)*128 + cs];
        } else {
            int j = i - 81920;
            int kb = j >> 12, ch = (j >> 10) & 3, rw = (j >> 3) & 127, e = j & 7;
            v = w2[rw*512 + kb*32 + sig(ch*8 + e)];
        }
        wcat8[i] = f2fp8(16.f * v);
    }
}

// ---------------- K1: qkv projection, LDS-transposed coalesced stores -------
__global__ __launch_bounds__(256) void k_qkv(
        const float* __restrict__ x, const ushort* __restrict__ w,
        const float* __restrict__ bias, ushort* __restrict__ qt,
        unsigned char* __restrict__ kv8, ushort* __restrict__ xb, int N) {
    __shared__ ushort sls[64 * 392];
    const int wave = threadIdx.x >> 6, lane = threadIdx.x & 63;
    const int l16 = lane & 15, l4 = lane >> 4;
    const int base = blockIdx.x * 64;

    short8 af[4][4];
    #pragma unroll
    for (int mt = 0; mt < 4; ++mt) {
        int row = base + mt*16 + l16;
        int rc = row < N ? row : N - 1;
        const float* p = x + (size_t)rc*128 + l4*8;
        #pragma unroll
        for (int kb = 0; kb < 4; ++kb) af[mt][kb] = load_frag_f32(p + kb*32);
    }
    #pragma unroll
    for (int mt = 0; mt < 4; ++mt) {
        int row = base + mt*16 + l16;
        if (row < N) {
            #pragma unroll
            for (int kb = 0; kb < 4; ++kb)
                *(short8*)(xb + (size_t)row*128 + kb*32 + l4*8) = af[mt][kb];
        }
    }
    #pragma unroll
    for (int i = 0; i < 6; ++i) {
        int col = (wave*6 + i)*16 + l16;
        const ushort* pw = w + (size_t)col*128 + l4*8;
        short8 bf[4];
        #pragma unroll
        for (int kb = 0; kb < 4; ++kb) bf[kb] = *(const short8*)(pw + kb*32);
        float bv = bias[col];
        #pragma unroll
        for (int mt = 0; mt < 4; ++mt) {
            f32x4 acc = {0.f, 0.f, 0.f, 0.f};
            #pragma unroll
            for (int kb = 0; kb < 4; ++kb)
                acc = __builtin_amdgcn_mfma_f32_16x16x32_bf16(af[mt][kb], bf[kb], acc, 0, 0, 0);
            #pragma unroll
            for (int r = 0; r < 4; ++r)
                sls[(mt*16 + l4*4 + r)*392 + col] = f2bf(acc[r] + bv);
        }
    }
    __syncthreads();
    {
        const int row = threadIdx.x >> 2, q = threadIdx.x & 3;
        const int grow = base + row;
        if (grow < N) {
            const ushort* sp = sls + row*392;
            #pragma unroll
            for (int j = 0; j < 4; ++j) {
                uint4 v = *(const uint4*)(sp + q*32 + j*8);
                *(uint4*)(qt + (size_t)grow*128 + q*32 + j*8) = v;
            }
            #pragma unroll
            for (int j = 0; j < 4; ++j) {
                unsigned wds[4];
                #pragma unroll
                for (int h = 0; h < 4; ++h) {
                    const ushort* e = sp + 128 + q*64 + j*16 + h*4;
                    wds[h] = pk4fp8(bf2f(e[0]), bf2f(e[1]), bf2f(e[2]), bf2f(e[3]));
                }
                *(uint4*)(kv8 + (size_t)grow*256 + q*64 + j*16) =
                    make_uint4(wds[0], wds[1], wds[2], wds[3]);
            }
        }
    }
}

// ---------------- K2: sampled attention, fp8 K/V gather (unchanged) ---------
__global__ __launch_bounds__(256) void k_attn(
        ushort* __restrict__ qt, const unsigned char* __restrict__ kv8,
        const int* __restrict__ samp, int N) {
    __shared__ float aw[4][8][17];
    __shared__ int   ai[4][16];
    const int wave = threadIdx.x >> 6, lane = threadIdx.x & 63;
    const int n = blockIdx.x * 4 + wave;
    if (n >= N) return;
    const int k  = lane & 15;
    const int hp = lane >> 4;
    const int h0 = hp, h1 = hp + 4;

    const int idx = samp[(size_t)n*16 + k];
    const ushort* qrow = qt + (size_t)n*128;
    const unsigned char* krow = kv8 + (size_t)idx*256;

    float s0 = dot16_q_k8(qrow + h0*16, krow + h0*16);
    float s1 = dot16_q_k8(qrow + h1*16, krow + h1*16);
    s0 *= 0.25f; s1 *= 0.25f;
    float m0 = s0, m1 = s1;
    #pragma unroll
    for (int off = 1; off < 16; off <<= 1) {
        m0 = fmaxf(m0, __shfl_xor(m0, off));
        m1 = fmaxf(m1, __shfl_xor(m1, off));
    }
    float e0 = __expf(s0 - m0), e1 = __expf(s1 - m1);
    float d0 = e0, d1 = e1;
    #pragma unroll
    for (int off = 1; off < 16; off <<= 1) {
        d0 += __shfl_xor(d0, off);
        d1 += __shfl_xor(d1, off);
    }
    aw[wave][h0][k] = e0 / d0;
    aw[wave][h1][k] = e1 / d1;
    if (hp == 0) ai[wave][k] = idx;

    const int c = lane & 15;
    const int g = lane >> 4;
    const int h = c >> 1;

    int rows[4];
    #pragma unroll
    for (int b = 0; b < 4; ++b) rows[b] = ai[wave][g + b*4];
    uint2 vv[4];
    #pragma unroll
    for (int b = 0; b < 4; ++b)
        vv[b] = *(const uint2*)(kv8 + (size_t)(unsigned)rows[b]*256 + 128 + c*8);
    float wk[4];
    #pragma unroll
    for (int b = 0; b < 4; ++b) wk[b] = aw[wave][h][g + b*4];

    float a8[8] = {0.f,0.f,0.f,0.f,0.f,0.f,0.f,0.f};
    #pragma unroll
    for (int b = 0; b < 4; ++b) {
        f32x2 p;
        p = __builtin_amdgcn_cvt_pk_f32_fp8(vv[b].x, false);
        a8[0] = fmaf(wk[b], p[0], a8[0]); a8[1] = fmaf(wk[b], p[1], a8[1]);
        p = __builtin_amdgcn_cvt_pk_f32_fp8(vv[b].x, true);
        a8[2] = fmaf(wk[b], p[0], a8[2]); a8[3] = fmaf(wk[b], p[1], a8[3]);
        p = __builtin_amdgcn_cvt_pk_f32_fp8(vv[b].y, false);
        a8[4] = fmaf(wk[b], p[0], a8[4]); a8[5] = fmaf(wk[b], p[1], a8[5]);
        p = __builtin_amdgcn_cvt_pk_f32_fp8(vv[b].y, true);
        a8[6] = fmaf(wk[b], p[0], a8[6]); a8[7] = fmaf(wk[b], p[1], a8[7]);
    }
    #pragma unroll
    for (int i = 0; i < 8; ++i) {
        a8[i] += __shfl_xor(a8[i], 16);
        a8[i] += __shfl_xor(a8[i], 32);
    }
    if (lane < 16) {
        unsigned lo = pk4fp8(8.f*a8[0], 8.f*a8[1], 8.f*a8[2], 8.f*a8[3]);
        unsigned hi = pk4fp8(8.f*a8[4], 8.f*a8[5], 8.f*a8[6], 8.f*a8[7]);
        *(uint2*)((unsigned char*)qt + (size_t)n*256 + c*8) = make_uint2(lo, hi);
    }
}

// ---------------- K3: fused tail — LDS: w1 64K + w2 64K + ybuf 32K = 160K ---
// Anti-spill round: yf16 state lives in per-thread LDS slots (not VGPRs, not
// scratch); wob8 streams from L2 (once per tile, broadcast across blocks);
// kb loop unroll 2, simple 4-deep chains. Target: kb-loop live set ~90 regs.
__global__ __launch_bounds__(512) void k_tail(
        const unsigned char* __restrict__ ctx8, const float* __restrict__ ob,
        const ushort* __restrict__ xb,
        const float* __restrict__ g1, const float* __restrict__ be1,
        const unsigned char* __restrict__ wcat8, const float* __restrict__ b1,
        const float* __restrict__ b2,
        const float* __restrict__ g2, const float* __restrict__ be2,
        float* __restrict__ out, int N) {
    __shared__ __align__(16) unsigned char smem[163840];   // 160 KB exactly
    const int tid = threadIdx.x;
    const int wave = tid >> 6, lane = tid & 63;
    const int l16 = lane & 15, l4 = lane >> 4;
    unsigned char* const ybuf = smem + 131072;              // [4][512][16B]

    // one-time LDS load of w1+w2 images: 131072B / 512thr = 16 x uint4
    {
        const uint4* src = (const uint4*)(wcat8 + 16384);
        #pragma unroll
        for (int b = 0; b < 2; ++b) {
            uint4 v[8];
            #pragma unroll
            for (int j = 0; j < 8; ++j) v[j] = src[(b*8 + j)*512 + tid];
            #pragma unroll
            for (int j = 0; j < 8; ++j)
                *(uint4*)(smem + ((size_t)(b*8 + j)*512 + tid)*16) = v[j];
        }
    }
    __syncthreads();

    const int ntiles = (N + 15) >> 4;
    const int nwv = gridDim.x * 8;
    for (int t = blockIdx.x * 8 + wave; t < ntiles; t += nwv) {
        const int row = t*16 + l16;
        const int rc = row < N ? row : N - 1;

        // ---- out-proj: A = wob8 streamed from global/L2, B = ctx8 ----
        f32x4 acc[8];
        #pragma unroll
        for (int nt = 0; nt < 8; ++nt) acc[nt] = (f32x4){0.f,0.f,0.f,0.f};
        {
            long cf[4];
            #pragma unroll
            for (int c = 0; c < 4; ++c)
                cf[c] = *(const long*)(ctx8 + (size_t)rc*256 + c*32 + l4*8);
            #pragma unroll
            for (int nt = 0; nt < 8; ++nt) {
                #pragma unroll
                for (int c = 0; c < 4; ++c) {
                    long wf = *(const long*)(wcat8 + (nt*16 + l16)*128 + (((c*4 + l4) ^ l16) << 3));
                    acc[nt] = __builtin_amdgcn_mfma_f32_16x16x32_fp8_fp8(wf, cf[c], acc[nt], 0, 0, 0);
                }
            }
        }

        // ---- bias + x residual + LN1 ----
        float sum0 = 0.f, sq0 = 0.f;
        #pragma unroll
        for (int nt = 0; nt < 8; ++nt) {
            f32x4 obv = *(const f32x4*)(ob + nt*16 + l4*4);
            uint2 xr = *(const uint2*)(xb + (size_t)rc*128 + nt*16 + l4*4);
            acc[nt][0] = acc[nt][0]*(1.f/128.f) + obv[0] + bflo(xr.x);
            acc[nt][1] = acc[nt][1]*(1.f/128.f) + obv[1] + bfhi(xr.x);
            acc[nt][2] = acc[nt][2]*(1.f/128.f) + obv[2] + bflo(xr.y);
            acc[nt][3] = acc[nt][3]*(1.f/128.f) + obv[3] + bfhi(xr.y);
            #pragma unroll
            for (int r = 0; r < 4; ++r) { sum0 += acc[nt][r]; sq0 += acc[nt][r]*acc[nt][r]; }
        }
        sum0 += __shfl_xor(sum0, 16); sum0 += __shfl_xor(sum0, 32);
        sq0  += __shfl_xor(sq0, 16);  sq0  += __shfl_xor(sq0, 32);
        float mean = sum0 * (1.f/128.f);
        float rstd = rsqrtf(sq0*(1.f/128.f) - mean*mean + EPS);

        // y -> ybuf (LDS, bf16, per-thread slot) + yf8 (fp8 regs, kb-loop input)
        long yf8[4];
        #pragma unroll
        for (int c = 0; c < 4; ++c) {
            float yv[8];
            short8 yw;
            #pragma unroll
            for (int half = 0; half < 2; ++half) {
                int nt = 2*c + half;
                f32x4 gv = *(const f32x4*)(g1 + nt*16 + l4*4);
                f32x4 bv = *(const f32x4*)(be1 + nt*16 + l4*4);
                #pragma unroll
                for (int r = 0; r < 4; ++r) {
                    float yn = (acc[nt][r] - mean) * rstd * gv[r] + bv[r];
                    yv[half*4 + r] = yn;
                    yw[half*4 + r] = (short)f2bf(yn);
                }
            }
            *(short8*)(ybuf + c*8192 + tid*16) = yw;
            unsigned lo = pk4fp8(yv[0], yv[1], yv[2], yv[3]);
            unsigned hi = pk4fp8(yv[4], yv[5], yv[6], yv[7]);
            yf8[c] = (long)(((unsigned long long)hi << 32) | lo);
        }

        // ---- FFN: w1/w2 from LDS; acc reused as acc2 ----
        f32x4 (&acc2)[8] = acc;
        #pragma unroll
        for (int nt = 0; nt < 8; ++nt) acc2[nt] = (f32x4){0.f,0.f,0.f,0.f};
        #pragma unroll 2
        for (int kb = 0; kb < 16; ++kb) {
            const unsigned char* w1b = smem + kb*4096;
            long wA[4], wB[4];
            #pragma unroll
            for (int c = 0; c < 4; ++c) {
                int so = ((c*4 + l4) ^ l16) << 3;
                wA[c] = *(const long*)(w1b + l16*128 + so);
                wB[c] = *(const long*)(w1b + (16 + l16)*128 + so);
            }
            f32x4 hA = {0.f,0.f,0.f,0.f}, hB = {0.f,0.f,0.f,0.f};
            #pragma unroll
            for (int c = 0; c < 4; ++c) {
                hA = __builtin_amdgcn_mfma_f32_16x16x32_fp8_fp8(wA[c], yf8[c], hA, 0, 0, 0);
                hB = __builtin_amdgcn_mfma_f32_16x16x32_fp8_fp8(wB[c], yf8[c], hB, 0, 0, 0);
            }
            f32x4 bA = *(const f32x4*)(b1 + kb*32 + l4*4);
            f32x4 bB = *(const f32x4*)(b1 + kb*32 + 16 + l4*4);
            float vA[4], vB[4];
            #pragma unroll
            for (int r = 0; r < 4; ++r) {
                vA[r] = fmaxf(hA[r]*0.0625f + bA[r], 0.f);
                vB[r] = fmaxf(hB[r]*0.0625f + bB[r], 0.f);
            }
            unsigned lo = pk4fp8(vA[0], vA[1], vA[2], vA[3]);
            unsigned hi = pk4fp8(vB[0], vB[1], vB[2], vB[3]);
            long hf8 = (long)(((unsigned long long)hi << 32) | lo);
            const unsigned char* w2b = smem + 65536 + kb*4096 + l4*1024;
            #pragma unroll
            for (int nt = 0; nt < 8; ++nt) {
                long w2f = *(const long*)(w2b + (nt*16 + l16)*8);
                acc2[nt] = __builtin_amdgcn_mfma_f32_16x16x32_fp8_fp8(w2f, hf8, acc2[nt], 0, 0, 0);
            }
        }

        // ---- s = y(ybuf) + ff/16 + b2, LN2, store ----
        float sum2 = 0.f, sq2 = 0.f;
        #pragma unroll
        for (int c = 0; c < 4; ++c) {
            short8 yw = *(const short8*)(ybuf + c*8192 + tid*16);
            #pragma unroll
            for (int half = 0; half < 2; ++half) {
                int nt = 2*c + half;
                f32x4 b2v = *(const f32x4*)(b2 + nt*16 + l4*4);
                #pragma unroll
                for (int r = 0; r < 4; ++r) {
                    float s = bf2f((ushort)yw[half*4 + r])
                              + acc2[nt][r]*0.0625f + b2v[r];
                    acc2[nt][r] = s; sum2 += s; sq2 += s*s;
                }
            }
        }
        sum2 += __shfl_xor(sum2, 16); sum2 += __shfl_xor(sum2, 32);
        sq2  += __shfl_xor(sq2, 16);  sq2  += __shfl_xor(sq2, 32);
        float mean2 = sum2 * (1.f/128.f);
        float rstd2 = rsqrtf(sq2*(1.f/128.f) - mean2*mean2 + EPS);
        if (row < N) {
            #pragma unroll
            for (int nt = 0; nt < 8; ++nt) {
                f32x4 gv = *(const f32x4*)(g2 + nt*16 + l4*4);
                f32x4 bv = *(const f32x4*)(be2 + nt*16 + l4*4);
                f32x4 o;
                #pragma unroll
                for (int r = 0; r < 4; ++r)
                    o[r] = (acc2[nt][r] - mean2) * rstd2 * gv[r] + bv[r];
                *(f32x4*)(out + (size_t)row*128 + nt*16 + l4*4) = o;
            }
        }
    }
}

extern "C" void kernel_launch(void* const* d_in, const int* in_sizes, int n_in,
                              void* d_out, int out_size, void* d_ws, size_t ws_size,
                              hipStream_t stream) {
    (void)n_in; (void)out_size; (void)ws_size;
    const float* x   = (const float*)d_in[0];
    const int*   smp = (const int*)  d_in[1];
    const float* ipw = (const float*)d_in[2];
    const float* ipb = (const float*)d_in[3];
    const float* ow  = (const float*)d_in[4];
    const float* ob  = (const float*)d_in[5];
    const float* w1  = (const float*)d_in[6];
    const float* b1  = (const float*)d_in[7];
    const float* w2  = (const float*)d_in[8];
    const float* b2  = (const float*)d_in[9];
    const float* g1  = (const float*)d_in[10];
    const float* be1 = (const float*)d_in[11];
    const float* g2  = (const float*)d_in[12];
    const float* be2 = (const float*)d_in[13];
    const int N = in_sizes[0] / 128;

    ushort* qt   = (ushort*)d_ws;                        // [N][128] bf16 q; ctx8 fp8 overlays
    unsigned char* kv8 = (unsigned char*)(qt + (size_t)N*128);   // [N][256] fp8 K|V
    ushort* wqb  = (ushort*)(kv8 + (size_t)N*256);       // 384*128 bf16
    unsigned char* wcat8 = (unsigned char*)(wqb + 49152);// 147456 B fp8 image
    ushort* xb   = (ushort*)(wcat8 + 147456);            // [N][128] bf16 x
    float*  outp = (float*)d_out;

    k_prep <<<576,       256, 0, stream>>>(ipw, ow, w1, w2, wqb, wcat8);
    k_qkv  <<<(N+63)/64, 256, 0, stream>>>(x, wqb, ipb, qt, kv8, xb, N);
    k_attn <<<(N+3)/4,   256, 0, stream>>>(qt, kv8, smp, N);
    k_tail <<<256,       512, 0, stream>>>((const unsigned char*)qt, ob, xb, g1, be1,
                                           wcat8, b1, b2, g2, be2, outp, N);
}

// Round 18
// 210.498 us; speedup vs baseline: 1.1070x; 1.1070x over previous
//
#include <hip/hip_runtime.h>
#include <hip/hip_bf16.h>

typedef __attribute__((ext_vector_type(8))) short short8;
typedef __attribute__((ext_vector_type(4))) float f32x4;
typedef __attribute__((ext_vector_type(2))) float f32x2;

#define EPS 1e-5f

__device__ __forceinline__ unsigned short f2bf(float f) {
    union { float f; unsigned u; } v; v.f = f;
    unsigned u = v.u;
    u += 0x7FFFu + ((u >> 16) & 1u);   // RNE
    return (unsigned short)(u >> 16);
}
__device__ __forceinline__ float bflo(unsigned u) {
    union { unsigned u; float f; } v; v.u = u << 16; return v.f;
}
__device__ __forceinline__ float bfhi(unsigned u) {
    union { unsigned u; float f; } v; v.u = u & 0xffff0000u; return v.f;
}
__device__ __forceinline__ float bf2f(ushort u) {
    union { unsigned u; float f; } v; v.u = ((unsigned)u) << 16; return v.f;
}
__device__ __forceinline__ unsigned char f2fp8(float v) {
    return (unsigned char)(__builtin_amdgcn_cvt_pk_fp8_f32(v, v, 0, false) & 0xff);
}
__device__ __forceinline__ unsigned pk4fp8(float a, float b, float c, float d) {
    unsigned u = __builtin_amdgcn_cvt_pk_fp8_f32(a, b, 0, false);
    u = __builtin_amdgcn_cvt_pk_fp8_f32(c, d, u, true);
    return u;
}
__device__ __forceinline__ int sig(int p) {            // sigma: acc-layout k-permutation
    return (((p >> 2) & 1) << 4) | (((p >> 3) & 3) << 2) | (p & 3);
}

// load 8 consecutive f32, convert to a bf16x8 MFMA fragment
__device__ __forceinline__ short8 load_frag_f32(const float* __restrict__ p) {
    f32x4 a = *(const f32x4*)p;
    f32x4 b = *(const f32x4*)(p + 4);
    short8 r;
    r[0] = (short)f2bf(a[0]); r[1] = (short)f2bf(a[1]);
    r[2] = (short)f2bf(a[2]); r[3] = (short)f2bf(a[3]);
    r[4] = (short)f2bf(b[0]); r[5] = (short)f2bf(b[1]);
    r[6] = (short)f2bf(b[2]); r[7] = (short)f2bf(b[3]);
    return r;
}

// dot(q[0..16) bf16, k[0..16) fp8) for one head
__device__ __forceinline__ float dot16_q_k8(const ushort* q, const unsigned char* kp) {
    uint4 kw = *(const uint4*)kp;
    const unsigned* qd = (const unsigned*)q;
    f32x2 a, b; float s = 0.f;
    a = __builtin_amdgcn_cvt_pk_f32_fp8(kw.x, false);
    b = __builtin_amdgcn_cvt_pk_f32_fp8(kw.x, true);
    s += a[0]*bflo(qd[0]) + a[1]*bfhi(qd[0]) + b[0]*bflo(qd[1]) + b[1]*bfhi(qd[1]);
    a = __builtin_amdgcn_cvt_pk_f32_fp8(kw.y, false);
    b = __builtin_amdgcn_cvt_pk_f32_fp8(kw.y, true);
    s += a[0]*bflo(qd[2]) + a[1]*bfhi(qd[2]) + b[0]*bflo(qd[3]) + b[1]*bfhi(qd[3]);
    a = __builtin_amdgcn_cvt_pk_f32_fp8(kw.z, false);
    b = __builtin_amdgcn_cvt_pk_f32_fp8(kw.z, true);
    s += a[0]*bflo(qd[4]) + a[1]*bfhi(qd[4]) + b[0]*bflo(qd[5]) + b[1]*bfhi(qd[5]);
    a = __builtin_amdgcn_cvt_pk_f32_fp8(kw.w, false);
    b = __builtin_amdgcn_cvt_pk_f32_fp8(kw.w, true);
    s += a[0]*bflo(qd[6]) + a[1]*bfhi(qd[6]) + b[0]*bflo(qd[7]) + b[1]*bfhi(qd[7]);
    return s;
}

// ---------------- K0: weight transforms (R12) --------------------------------
__global__ __launch_bounds__(256) void k_prep(
        const float* __restrict__ ipw, const float* __restrict__ ow,
        const float* __restrict__ w1, const float* __restrict__ w2,
        ushort* __restrict__ wqb, unsigned char* __restrict__ wcat8) {
    int i = blockIdx.x * 256 + threadIdx.x;
    if (i < 49152) wqb[i] = f2bf(ipw[i]);
    if (i < 147456) {
        float v;
        if (i < 16384) {
            int r = i >> 7, s = (i >> 3) & 15, e = i & 7;
            v = ow[r*128 + ((s ^ (r & 15)) << 3) + e];
        } else if (i < 81920) {
            int j = i - 16384;
            int kb = j >> 12, r = (j >> 7) & 31, s = (j >> 3) & 15, e = j & 7;
            int cp = ((s ^ (r & 15)) << 3) + e;
            int cs = (cp & ~31) | sig(cp & 31);
            v = w1[(kb*32 + r)*128 + cs];
        } else {
            int j = i - 81920;
            int kb = j >> 12, ch = (j >> 10) & 3, rw = (j >> 3) & 127, e = j & 7;
            v = w2[rw*512 + kb*32 + sig(ch*8 + e)];
        }
        wcat8[i] = f2fp8(16.f * v);
    }
}

// ---------------- K1: qkv projection, LDS-transposed coalesced stores -------
__global__ __launch_bounds__(256) void k_qkv(
        const float* __restrict__ x, const ushort* __restrict__ w,
        const float* __restrict__ bias, ushort* __restrict__ qt,
        unsigned char* __restrict__ kv8, ushort* __restrict__ xb, int N) {
    __shared__ ushort sls[64 * 392];
    const int wave = threadIdx.x >> 6, lane = threadIdx.x & 63;
    const int l16 = lane & 15, l4 = lane >> 4;
    const int base = blockIdx.x * 64;

    short8 af[4][4];
    #pragma unroll
    for (int mt = 0; mt < 4; ++mt) {
        int row = base + mt*16 + l16;
        int rc = row < N ? row : N - 1;
        const float* p = x + (size_t)rc*128 + l4*8;
        #pragma unroll
        for (int kb = 0; kb < 4; ++kb) af[mt][kb] = load_frag_f32(p + kb*32);
    }
    #pragma unroll
    for (int mt = 0; mt < 4; ++mt) {
        int row = base + mt*16 + l16;
        if (row < N) {
            #pragma unroll
            for (int kb = 0; kb < 4; ++kb)
                *(short8*)(xb + (size_t)row*128 + kb*32 + l4*8) = af[mt][kb];
        }
    }
    #pragma unroll
    for (int i = 0; i < 6; ++i) {
        int col = (wave*6 + i)*16 + l16;
        const ushort* pw = w + (size_t)col*128 + l4*8;
        short8 bf[4];
        #pragma unroll
        for (int kb = 0; kb < 4; ++kb) bf[kb] = *(const short8*)(pw + kb*32);
        float bv = bias[col];
        #pragma unroll
        for (int mt = 0; mt < 4; ++mt) {
            f32x4 acc = {0.f, 0.f, 0.f, 0.f};
            #pragma unroll
            for (int kb = 0; kb < 4; ++kb)
                acc = __builtin_amdgcn_mfma_f32_16x16x32_bf16(af[mt][kb], bf[kb], acc, 0, 0, 0);
            #pragma unroll
            for (int r = 0; r < 4; ++r)
                sls[(mt*16 + l4*4 + r)*392 + col] = f2bf(acc[r] + bv);
        }
    }
    __syncthreads();
    {
        const int row = threadIdx.x >> 2, q = threadIdx.x & 3;
        const int grow = base + row;
        if (grow < N) {
            const ushort* sp = sls + row*392;
            #pragma unroll
            for (int j = 0; j < 4; ++j) {
                uint4 v = *(const uint4*)(sp + q*32 + j*8);
                *(uint4*)(qt + (size_t)grow*128 + q*32 + j*8) = v;
            }
            #pragma unroll
            for (int j = 0; j < 4; ++j) {
                unsigned wds[4];
                #pragma unroll
                for (int h = 0; h < 4; ++h) {
                    const ushort* e = sp + 128 + q*64 + j*16 + h*4;
                    wds[h] = pk4fp8(bf2f(e[0]), bf2f(e[1]), bf2f(e[2]), bf2f(e[3]));
                }
                *(uint4*)(kv8 + (size_t)grow*256 + q*64 + j*16) =
                    make_uint4(wds[0], wds[1], wds[2], wds[3]);
            }
        }
    }
}

// ---------------- K2: sampled attention, fp8 K/V gather (R12) ---------------
__global__ __launch_bounds__(256) void k_attn(
        ushort* __restrict__ qt, const unsigned char* __restrict__ kv8,
        const int* __restrict__ samp, int N) {
    __shared__ float aw[4][8][17];
    __shared__ int   ai[4][16];
    const int wave = threadIdx.x >> 6, lane = threadIdx.x & 63;
    const int n = blockIdx.x * 4 + wave;
    if (n >= N) return;
    const int k  = lane & 15;
    const int hp = lane >> 4;
    const int h0 = hp, h1 = hp + 4;

    const int idx = samp[(size_t)n*16 + k];
    const ushort* qrow = qt + (size_t)n*128;
    const unsigned char* krow = kv8 + (size_t)idx*256;

    float s0 = dot16_q_k8(qrow + h0*16, krow + h0*16);
    float s1 = dot16_q_k8(qrow + h1*16, krow + h1*16);
    s0 *= 0.25f; s1 *= 0.25f;
    float m0 = s0, m1 = s1;
    #pragma unroll
    for (int off = 1; off < 16; off <<= 1) {
        m0 = fmaxf(m0, __shfl_xor(m0, off));
        m1 = fmaxf(m1, __shfl_xor(m1, off));
    }
    float e0 = __expf(s0 - m0), e1 = __expf(s1 - m1);
    float d0 = e0, d1 = e1;
    #pragma unroll
    for (int off = 1; off < 16; off <<= 1) {
        d0 += __shfl_xor(d0, off);
        d1 += __shfl_xor(d1, off);
    }
    aw[wave][h0][k] = e0 / d0;
    aw[wave][h1][k] = e1 / d1;
    if (hp == 0) ai[wave][k] = idx;

    const int c = lane & 15;
    const int g = lane >> 4;
    const int h = c >> 1;

    int rows[4];
    #pragma unroll
    for (int b = 0; b < 4; ++b) rows[b] = ai[wave][g + b*4];
    uint2 vv[4];
    #pragma unroll
    for (int b = 0; b < 4; ++b)
        vv[b] = *(const uint2*)(kv8 + (size_t)(unsigned)rows[b]*256 + 128 + c*8);
    float wk[4];
    #pragma unroll
    for (int b = 0; b < 4; ++b) wk[b] = aw[wave][h][g + b*4];

    float a8[8] = {0.f,0.f,0.f,0.f,0.f,0.f,0.f,0.f};
    #pragma unroll
    for (int b = 0; b < 4; ++b) {
        f32x2 p;
        p = __builtin_amdgcn_cvt_pk_f32_fp8(vv[b].x, false);
        a8[0] = fmaf(wk[b], p[0], a8[0]); a8[1] = fmaf(wk[b], p[1], a8[1]);
        p = __builtin_amdgcn_cvt_pk_f32_fp8(vv[b].x, true);
        a8[2] = fmaf(wk[b], p[0], a8[2]); a8[3] = fmaf(wk[b], p[1], a8[3]);
        p = __builtin_amdgcn_cvt_pk_f32_fp8(vv[b].y, false);
        a8[4] = fmaf(wk[b], p[0], a8[4]); a8[5] = fmaf(wk[b], p[1], a8[5]);
        p = __builtin_amdgcn_cvt_pk_f32_fp8(vv[b].y, true);
        a8[6] = fmaf(wk[b], p[0], a8[6]); a8[7] = fmaf(wk[b], p[1], a8[7]);
    }
    #pragma unroll
    for (int i = 0; i < 8; ++i) {
        a8[i] += __shfl_xor(a8[i], 16);
        a8[i] += __shfl_xor(a8[i], 32);
    }
    if (lane < 16) {
        unsigned lo = pk4fp8(8.f*a8[0], 8.f*a8[1], 8.f*a8[2], 8.f*a8[3]);
        unsigned hi = pk4fp8(8.f*a8[4], 8.f*a8[5], 8.f*a8[6], 8.f*a8[7]);
        *(uint2*)((unsigned char*)qt + (size_t)n*256 + c*8) = make_uint2(lo, hi);
    }
}

// ---------------- K3: fused tail — R12 EXACT (best measured: 96us) ----------
// 144KB LDS (all weights resident), 512 thr, mt=2, acc2 aliases acc,
// launch_bounds(512,2). Known to report VGPR=128 with ~85MB spill — measured
// FASTER than every anti-spill variant (R13 mt=1, R16 chain-split, R17 LDS
// state). The ~96us attractor is robust to all structural levers tried.
__global__ __launch_bounds__(512, 2) void k_tail(
        const unsigned char* __restrict__ ctx8, const float* __restrict__ ob,
        const ushort* __restrict__ xb,
        const float* __restrict__ g1, const float* __restrict__ be1,
        const unsigned char* __restrict__ wcat8, const float* __restrict__ b1,
        const float* __restrict__ b2,
        const float* __restrict__ g2, const float* __restrict__ be2,
        float* __restrict__ out, int N) {
    __shared__ __align__(16) unsigned char smem[147456];
    const int tid = threadIdx.x;
    const int wave = tid >> 6, lane = tid & 63;
    const int l16 = lane & 15, l4 = lane >> 4;

    // one-time weight load: 147456B / 512thr = 18 x uint4 per thread
    {
        const uint4* src = (const uint4*)wcat8;
        #pragma unroll
        for (int b = 0; b < 3; ++b) {
            uint4 v[6];
            #pragma unroll
            for (int j = 0; j < 6; ++j) v[j] = src[(b*6 + j)*512 + tid];
            #pragma unroll
            for (int j = 0; j < 6; ++j)
                *(uint4*)(smem + ((size_t)(b*6 + j)*512 + tid)*16) = v[j];
        }
    }
    __syncthreads();

    const int ntiles = (N + 31) >> 5;
    const int nwv = gridDim.x * 8;
    for (int t = blockIdx.x * 8 + wave; t < ntiles; t += nwv) {
        int row[2], rc[2];
        row[0] = t*32 + l16;      rc[0] = row[0] < N ? row[0] : N - 1;
        row[1] = t*32 + 16 + l16; rc[1] = row[1] < N ? row[1] : N - 1;

        // ---- out-proj: A = wob8 (LDS), B = ctx8 (global fp8) ----
        f32x4 acc[2][8];
        #pragma unroll
        for (int mt = 0; mt < 2; ++mt)
            #pragma unroll
            for (int nt = 0; nt < 8; ++nt) acc[mt][nt] = (f32x4){0.f,0.f,0.f,0.f};
        {
            long cf[2][4];
            #pragma unroll
            for (int mt = 0; mt < 2; ++mt)
                #pragma unroll
                for (int c = 0; c < 4; ++c)
                    cf[mt][c] = *(const long*)(ctx8 + (size_t)rc[mt]*256 + c*32 + l4*8);
            #pragma unroll
            for (int nt = 0; nt < 8; ++nt) {
                #pragma unroll
                for (int c = 0; c < 4; ++c) {
                    long wf = *(const long*)(smem + (nt*16 + l16)*128 + (((c*4 + l4) ^ l16) << 3));
                    acc[0][nt] = __builtin_amdgcn_mfma_f32_16x16x32_fp8_fp8(wf, cf[0][c], acc[0][nt], 0, 0, 0);
                    acc[1][nt] = __builtin_amdgcn_mfma_f32_16x16x32_fp8_fp8(wf, cf[1][c], acc[1][nt], 0, 0, 0);
                }
            }
        }

        // ---- bias + x residual + LN1 ----
        float sum0 = 0.f, sq0 = 0.f, sum1 = 0.f, sq1 = 0.f;
        #pragma unroll
        for (int nt = 0; nt < 8; ++nt) {
            f32x4 obv = *(const f32x4*)(ob + nt*16 + l4*4);
            uint2 xr0 = *(const uint2*)(xb + (size_t)rc[0]*128 + nt*16 + l4*4);
            uint2 xr1 = *(const uint2*)(xb + (size_t)rc[1]*128 + nt*16 + l4*4);
            acc[0][nt][0] = acc[0][nt][0]*(1.f/128.f) + obv[0] + bflo(xr0.x);
            acc[0][nt][1] = acc[0][nt][1]*(1.f/128.f) + obv[1] + bfhi(xr0.x);
            acc[0][nt][2] = acc[0][nt][2]*(1.f/128.f) + obv[2] + bflo(xr0.y);
            acc[0][nt][3] = acc[0][nt][3]*(1.f/128.f) + obv[3] + bfhi(xr0.y);
            acc[1][nt][0] = acc[1][nt][0]*(1.f/128.f) + obv[0] + bflo(xr1.x);
            acc[1][nt][1] = acc[1][nt][1]*(1.f/128.f) + obv[1] + bfhi(xr1.x);
            acc[1][nt][2] = acc[1][nt][2]*(1.f/128.f) + obv[2] + bflo(xr1.y);
            acc[1][nt][3] = acc[1][nt][3]*(1.f/128.f) + obv[3] + bfhi(xr1.y);
            #pragma unroll
            for (int r = 0; r < 4; ++r) {
                sum0 += acc[0][nt][r]; sq0 += acc[0][nt][r]*acc[0][nt][r];
                sum1 += acc[1][nt][r]; sq1 += acc[1][nt][r]*acc[1][nt][r];
            }
        }
        sum0 += __shfl_xor(sum0, 16); sum0 += __shfl_xor(sum0, 32);
        sq0  += __shfl_xor(sq0, 16);  sq0  += __shfl_xor(sq0, 32);
        sum1 += __shfl_xor(sum1, 16); sum1 += __shfl_xor(sum1, 32);
        sq1  += __shfl_xor(sq1, 16);  sq1  += __shfl_xor(sq1, 32);
        float mean[2], rstd[2];
        mean[0] = sum0 * (1.f/128.f);
        rstd[0] = rsqrtf(sq0*(1.f/128.f) - mean[0]*mean[0] + EPS);
        mean[1] = sum1 * (1.f/128.f);
        rstd[1] = rsqrtf(sq1*(1.f/128.f) - mean[1]*mean[1] + EPS);

        // y -> bf16 (residual) + fp8 (MFMA B-operand)
        short8 yf16[2][4];
        long   yf8[2][4];
        #pragma unroll
        for (int mt = 0; mt < 2; ++mt) {
            #pragma unroll
            for (int c = 0; c < 4; ++c) {
                float yv[8];
                #pragma unroll
                for (int half = 0; half < 2; ++half) {
                    int nt = 2*c + half;
                    f32x4 gv = *(const f32x4*)(g1 + nt*16 + l4*4);
                    f32x4 bv = *(const f32x4*)(be1 + nt*16 + l4*4);
                    #pragma unroll
                    for (int r = 0; r < 4; ++r) {
                        float yn = (acc[mt][nt][r] - mean[mt]) * rstd[mt] * gv[r] + bv[r];
                        yv[half*4 + r] = yn;
                        yf16[mt][c][half*4 + r] = (short)f2bf(yn);
                    }
                }
                unsigned lo = pk4fp8(yv[0], yv[1], yv[2], yv[3]);
                unsigned hi = pk4fp8(yv[4], yv[5], yv[6], yv[7]);
                yf8[mt][c] = (long)(((unsigned long long)hi << 32) | lo);
            }
        }

        // ---- FFN: acc reused as acc2 ----
        f32x4 (&acc2)[2][8] = acc;
        #pragma unroll
        for (int mt = 0; mt < 2; ++mt)
            #pragma unroll
            for (int nt = 0; nt < 8; ++nt) acc2[mt][nt] = (f32x4){0.f,0.f,0.f,0.f};
        #pragma unroll 4
        for (int kb = 0; kb < 16; ++kb) {
            const unsigned char* w1b = smem + 16384 + kb*4096;
            long wA[4], wB[4];
            #pragma unroll
            for (int c = 0; c < 4; ++c) {
                int so = ((c*4 + l4) ^ l16) << 3;
                wA[c] = *(const long*)(w1b + l16*128 + so);
                wB[c] = *(const long*)(w1b + (16 + l16)*128 + so);
            }
            f32x4 hA[2] = {{0.f,0.f,0.f,0.f},{0.f,0.f,0.f,0.f}};
            f32x4 hB[2] = {{0.f,0.f,0.f,0.f},{0.f,0.f,0.f,0.f}};
            #pragma unroll
            for (int c = 0; c < 4; ++c)
                #pragma unroll
                for (int mt = 0; mt < 2; ++mt) {
                    hA[mt] = __builtin_amdgcn_mfma_f32_16x16x32_fp8_fp8(wA[c], yf8[mt][c], hA[mt], 0, 0, 0);
                    hB[mt] = __builtin_amdgcn_mfma_f32_16x16x32_fp8_fp8(wB[c], yf8[mt][c], hB[mt], 0, 0, 0);
                }
            f32x4 bA = *(const f32x4*)(b1 + kb*32 + l4*4);
            f32x4 bB = *(const f32x4*)(b1 + kb*32 + 16 + l4*4);
            long hf8[2];
            #pragma unroll
            for (int mt = 0; mt < 2; ++mt) {
                float vA[4], vB[4];
                #pragma unroll
                for (int r = 0; r < 4; ++r) {
                    vA[r] = fmaxf(hA[mt][r]*0.0625f + bA[r], 0.f);
                    vB[r] = fmaxf(hB[mt][r]*0.0625f + bB[r], 0.f);
                }
                unsigned lo = pk4fp8(vA[0], vA[1], vA[2], vA[3]);
                unsigned hi = pk4fp8(vB[0], vB[1], vB[2], vB[3]);
                hf8[mt] = (long)(((unsigned long long)hi << 32) | lo);
            }
            const unsigned char* w2b = smem + 81920 + kb*4096 + l4*1024;
            #pragma unroll
            for (int nt = 0; nt < 8; ++nt) {
                long w2f = *(const long*)(w2b + (nt*16 + l16)*8);
                acc2[0][nt] = __builtin_amdgcn_mfma_f32_16x16x32_fp8_fp8(w2f, hf8[0], acc2[0][nt], 0, 0, 0);
                acc2[1][nt] = __builtin_amdgcn_mfma_f32_16x16x32_fp8_fp8(w2f, hf8[1], acc2[1][nt], 0, 0, 0);
            }
        }

        // ---- s = y + ff/16 + b2, LN2, store ----
        #pragma unroll
        for (int mt = 0; mt < 2; ++mt) {
            float sum2 = 0.f, sq2 = 0.f;
            #pragma unroll
            for (int nt = 0; nt < 8; ++nt) {
                f32x4 b2v = *(const f32x4*)(b2 + nt*16 + l4*4);
                #pragma unroll
                for (int r = 0; r < 4; ++r) {
                    float s = bf2f((ushort)yf16[mt][nt >> 1][(nt & 1)*4 + r])
                              + acc2[mt][nt][r]*0.0625f + b2v[r];
                    acc2[mt][nt][r] = s; sum2 += s; sq2 += s*s;
                }
            }
            sum2 += __shfl_xor(sum2, 16); sum2 += __shfl_xor(sum2, 32);
            sq2  += __shfl_xor(sq2, 16);  sq2  += __shfl_xor(sq2, 32);
            float mean2 = sum2 * (1.f/128.f);
            float rstd2 = rsqrtf(sq2*(1.f/128.f) - mean2*mean2 + EPS);
            if (row[mt] < N) {
                #pragma unroll
                for (int nt = 0; nt < 8; ++nt) {
                    f32x4 gv = *(const f32x4*)(g2 + nt*16 + l4*4);
                    f32x4 bv = *(const f32x4*)(be2 + nt*16 + l4*4);
                    f32x4 o;
                    #pragma unroll
                    for (int r = 0; r < 4; ++r)
                        o[r] = (acc2[mt][nt][r] - mean2) * rstd2 * gv[r] + bv[r];
                    *(f32x4*)(out + (size_t)row[mt]*128 + nt*16 + l4*4) = o;
                }
            }
        }
    }
}

extern "C" void kernel_launch(void* const* d_in, const int* in_sizes, int n_in,
                              void* d_out, int out_size, void* d_ws, size_t ws_size,
                              hipStream_t stream) {
    (void)n_in; (void)out_size; (void)ws_size;
    const float* x   = (const float*)d_in[0];
    const int*   smp = (const int*)  d_in[1];
    const float* ipw = (const float*)d_in[2];
    const float* ipb = (const float*)d_in[3];
    const float* ow  = (const float*)d_in[4];
    const float* ob  = (const float*)d_in[5];
    const float* w1  = (const float*)d_in[6];
    const float* b1  = (const float*)d_in[7];
    const float* w2  = (const float*)d_in[8];
    const float* b2  = (const float*)d_in[9];
    const float* g1  = (const float*)d_in[10];
    const float* be1 = (const float*)d_in[11];
    const float* g2  = (const float*)d_in[12];
    const float* be2 = (const float*)d_in[13];
    const int N = in_sizes[0] / 128;

    ushort* qt   = (ushort*)d_ws;                        // [N][128] bf16 q; ctx8 fp8 overlays
    unsigned char* kv8 = (unsigned char*)(qt + (size_t)N*128);   // [N][256] fp8 K|V
    ushort* wqb  = (ushort*)(kv8 + (size_t)N*256);       // 384*128 bf16
    unsigned char* wcat8 = (unsigned char*)(wqb + 49152);// 147456 B fp8 LDS image
    ushort* xb   = (ushort*)(wcat8 + 147456);            // [N][128] bf16 x
    float*  outp = (float*)d_out;

    k_prep <<<576,       256, 0, stream>>>(ipw, ow, w1, w2, wqb, wcat8);
    k_qkv  <<<(N+63)/64, 256, 0, stream>>>(x, wqb, ipb, qt, kv8, xb, N);
    k_attn <<<(N+3)/4,   256, 0, stream>>>(qt, kv8, smp, N);
    k_tail <<<256,       512, 0, stream>>>((const unsigned char*)qt, ob, xb, g1, be1,
                                           wcat8, b1, b2, g2, be2, outp, N);
}

// Round 19
// 206.950 us; speedup vs baseline: 1.1260x; 1.0171x over previous
//
#include <hip/hip_runtime.h>
#include <hip/hip_bf16.h>

typedef __attribute__((ext_vector_type(8))) short short8;
typedef __attribute__((ext_vector_type(4))) float f32x4;
typedef __attribute__((ext_vector_type(2))) float f32x2;

#define EPS 1e-5f

__device__ __forceinline__ unsigned short f2bf(float f) {
    union { float f; unsigned u; } v; v.f = f;
    unsigned u = v.u;
    u += 0x7FFFu + ((u >> 16) & 1u);   // RNE
    return (unsigned short)(u >> 16);
}
__device__ __forceinline__ float bflo(unsigned u) {
    union { unsigned u; float f; } v; v.u = u << 16; return v.f;
}
__device__ __forceinline__ float bfhi(unsigned u) {
    union { unsigned u; float f; } v; v.u = u & 0xffff0000u; return v.f;
}
__device__ __forceinline__ float bf2f(ushort u) {
    union { unsigned u; float f; } v; v.u = ((unsigned)u) << 16; return v.f;
}
__device__ __forceinline__ unsigned char f2fp8(float v) {
    return (unsigned char)(__builtin_amdgcn_cvt_pk_fp8_f32(v, v, 0, false) & 0xff);
}
__device__ __forceinline__ unsigned pk4fp8(float a, float b, float c, float d) {
    unsigned u = __builtin_amdgcn_cvt_pk_fp8_f32(a, b, 0, false);
    u = __builtin_amdgcn_cvt_pk_fp8_f32(c, d, u, true);
    return u;
}
__device__ __forceinline__ int sig(int p) {            // sigma: acc-layout k-permutation
    return (((p >> 2) & 1) << 4) | (((p >> 3) & 3) << 2) | (p & 3);
}

// load 8 consecutive f32, convert to a bf16x8 MFMA fragment
__device__ __forceinline__ short8 load_frag_f32(const float* __restrict__ p) {
    f32x4 a = *(const f32x4*)p;
    f32x4 b = *(const f32x4*)(p + 4);
    short8 r;
    r[0] = (short)f2bf(a[0]); r[1] = (short)f2bf(a[1]);
    r[2] = (short)f2bf(a[2]); r[3] = (short)f2bf(a[3]);
    r[4] = (short)f2bf(b[0]); r[5] = (short)f2bf(b[1]);
    r[6] = (short)f2bf(b[2]); r[7] = (short)f2bf(b[3]);
    return r;
}

// dot(q[0..16) bf16, k[0..16) fp8) for one head
__device__ __forceinline__ float dot16_q_k8(const ushort* q, const unsigned char* kp) {
    uint4 kw = *(const uint4*)kp;
    const unsigned* qd = (const unsigned*)q;
    f32x2 a, b; float s = 0.f;
    a = __builtin_amdgcn_cvt_pk_f32_fp8(kw.x, false);
    b = __builtin_amdgcn_cvt_pk_f32_fp8(kw.x, true);
    s += a[0]*bflo(qd[0]) + a[1]*bfhi(qd[0]) + b[0]*bflo(qd[1]) + b[1]*bfhi(qd[1]);
    a = __builtin_amdgcn_cvt_pk_f32_fp8(kw.y, false);
    b = __builtin_amdgcn_cvt_pk_f32_fp8(kw.y, true);
    s += a[0]*bflo(qd[2]) + a[1]*bfhi(qd[2]) + b[0]*bflo(qd[3]) + b[1]*bfhi(qd[3]);
    a = __builtin_amdgcn_cvt_pk_f32_fp8(kw.z, false);
    b = __builtin_amdgcn_cvt_pk_f32_fp8(kw.z, true);
    s += a[0]*bflo(qd[4]) + a[1]*bfhi(qd[4]) + b[0]*bflo(qd[5]) + b[1]*bfhi(qd[5]);
    a = __builtin_amdgcn_cvt_pk_f32_fp8(kw.w, false);
    b = __builtin_amdgcn_cvt_pk_f32_fp8(kw.w, true);
    s += a[0]*bflo(qd[6]) + a[1]*bfhi(qd[6]) + b[0]*bflo(qd[7]) + b[1]*bfhi(qd[7]);
    return s;
}

// ---------------- K0: weight transforms (R12) --------------------------------
__global__ __launch_bounds__(256) void k_prep(
        const float* __restrict__ ipw, const float* __restrict__ ow,
        const float* __restrict__ w1, const float* __restrict__ w2,
        ushort* __restrict__ wqb, unsigned char* __restrict__ wcat8) {
    int i = blockIdx.x * 256 + threadIdx.x;
    if (i < 49152) wqb[i] = f2bf(ipw[i]);
    if (i < 147456) {
        float v;
        if (i < 16384) {
            int r = i >> 7, s = (i >> 3) & 15, e = i & 7;
            v = ow[r*128 + ((s ^ (r & 15)) << 3) + e];
        } else if (i < 81920) {
            int j = i - 16384;
            int kb = j >> 12, r = (j >> 7) & 31, s = (j >> 3) & 15, e = j & 7;
            int cp = ((s ^ (r & 15)) << 3) + e;
            int cs = (cp & ~31) | sig(cp & 31);
            v = w1[(kb*32 + r)*128 + cs];
        } else {
            int j = i - 81920;
            int kb = j >> 12, ch = (j >> 10) & 3, rw = (j >> 3) & 127, e = j & 7;
            v = w2[rw*512 + kb*32 + sig(ch*8 + e)];
        }
        wcat8[i] = f2fp8(16.f * v);
    }
}

// ---------------- K1: qkv projection, LDS-transposed coalesced stores -------
__global__ __launch_bounds__(256) void k_qkv(
        const float* __restrict__ x, const ushort* __restrict__ w,
        const float* __restrict__ bias, ushort* __restrict__ qt,
        unsigned char* __restrict__ kv8, ushort* __restrict__ xb, int N) {
    __shared__ ushort sls[64 * 392];
    const int wave = threadIdx.x >> 6, lane = threadIdx.x & 63;
    const int l16 = lane & 15, l4 = lane >> 4;
    const int base = blockIdx.x * 64;

    short8 af[4][4];
    #pragma unroll
    for (int mt = 0; mt < 4; ++mt) {
        int row = base + mt*16 + l16;
        int rc = row < N ? row : N - 1;
        const float* p = x + (size_t)rc*128 + l4*8;
        #pragma unroll
        for (int kb = 0; kb < 4; ++kb) af[mt][kb] = load_frag_f32(p + kb*32);
    }
    #pragma unroll
    for (int mt = 0; mt < 4; ++mt) {
        int row = base + mt*16 + l16;
        if (row < N) {
            #pragma unroll
            for (int kb = 0; kb < 4; ++kb)
                *(short8*)(xb + (size_t)row*128 + kb*32 + l4*8) = af[mt][kb];
        }
    }
    #pragma unroll
    for (int i = 0; i < 6; ++i) {
        int col = (wave*6 + i)*16 + l16;
        const ushort* pw = w + (size_t)col*128 + l4*8;
        short8 bf[4];
        #pragma unroll
        for (int kb = 0; kb < 4; ++kb) bf[kb] = *(const short8*)(pw + kb*32);
        float bv = bias[col];
        #pragma unroll
        for (int mt = 0; mt < 4; ++mt) {
            f32x4 acc = {0.f, 0.f, 0.f, 0.f};
            #pragma unroll
            for (int kb = 0; kb < 4; ++kb)
                acc = __builtin_amdgcn_mfma_f32_16x16x32_bf16(af[mt][kb], bf[kb], acc, 0, 0, 0);
            #pragma unroll
            for (int r = 0; r < 4; ++r)
                sls[(mt*16 + l4*4 + r)*392 + col] = f2bf(acc[r] + bv);
        }
    }
    __syncthreads();
    {
        const int row = threadIdx.x >> 2, q = threadIdx.x & 3;
        const int grow = base + row;
        if (grow < N) {
            const ushort* sp = sls + row*392;
            #pragma unroll
            for (int j = 0; j < 4; ++j) {
                uint4 v = *(const uint4*)(sp + q*32 + j*8);
                *(uint4*)(qt + (size_t)grow*128 + q*32 + j*8) = v;
            }
            #pragma unroll
            for (int j = 0; j < 4; ++j) {
                unsigned wds[4];
                #pragma unroll
                for (int h = 0; h < 4; ++h) {
                    const ushort* e = sp + 128 + q*64 + j*16 + h*4;
                    wds[h] = pk4fp8(bf2f(e[0]), bf2f(e[1]), bf2f(e[2]), bf2f(e[3]));
                }
                *(uint4*)(kv8 + (size_t)grow*256 + q*64 + j*16) =
                    make_uint4(wds[0], wds[1], wds[2], wds[3]);
            }
        }
    }
}

// ---------------- K2: sampled attention, fp8 K/V gather (R12) ---------------
__global__ __launch_bounds__(256) void k_attn(
        ushort* __restrict__ qt, const unsigned char* __restrict__ kv8,
        const int* __restrict__ samp, int N) {
    __shared__ float aw[4][8][17];
    __shared__ int   ai[4][16];
    const int wave = threadIdx.x >> 6, lane = threadIdx.x & 63;
    const int n = blockIdx.x * 4 + wave;
    if (n >= N) return;
    const int k  = lane & 15;
    const int hp = lane >> 4;
    const int h0 = hp, h1 = hp + 4;

    const int idx = samp[(size_t)n*16 + k];
    const ushort* qrow = qt + (size_t)n*128;
    const unsigned char* krow = kv8 + (size_t)idx*256;

    float s0 = dot16_q_k8(qrow + h0*16, krow + h0*16);
    float s1 = dot16_q_k8(qrow + h1*16, krow + h1*16);
    s0 *= 0.25f; s1 *= 0.25f;
    float m0 = s0, m1 = s1;
    #pragma unroll
    for (int off = 1; off < 16; off <<= 1) {
        m0 = fmaxf(m0, __shfl_xor(m0, off));
        m1 = fmaxf(m1, __shfl_xor(m1, off));
    }
    float e0 = __expf(s0 - m0), e1 = __expf(s1 - m1);
    float d0 = e0, d1 = e1;
    #pragma unroll
    for (int off = 1; off < 16; off <<= 1) {
        d0 += __shfl_xor(d0, off);
        d1 += __shfl_xor(d1, off);
    }
    aw[wave][h0][k] = e0 / d0;
    aw[wave][h1][k] = e1 / d1;
    if (hp == 0) ai[wave][k] = idx;

    const int c = lane & 15;
    const int g = lane >> 4;
    const int h = c >> 1;

    int rows[4];
    #pragma unroll
    for (int b = 0; b < 4; ++b) rows[b] = ai[wave][g + b*4];
    uint2 vv[4];
    #pragma unroll
    for (int b = 0; b < 4; ++b)
        vv[b] = *(const uint2*)(kv8 + (size_t)(unsigned)rows[b]*256 + 128 + c*8);
    float wk[4];
    #pragma unroll
    for (int b = 0; b < 4; ++b) wk[b] = aw[wave][h][g + b*4];

    float a8[8] = {0.f,0.f,0.f,0.f,0.f,0.f,0.f,0.f};
    #pragma unroll
    for (int b = 0; b < 4; ++b) {
        f32x2 p;
        p = __builtin_amdgcn_cvt_pk_f32_fp8(vv[b].x, false);
        a8[0] = fmaf(wk[b], p[0], a8[0]); a8[1] = fmaf(wk[b], p[1], a8[1]);
        p = __builtin_amdgcn_cvt_pk_f32_fp8(vv[b].x, true);
        a8[2] = fmaf(wk[b], p[0], a8[2]); a8[3] = fmaf(wk[b], p[1], a8[3]);
        p = __builtin_amdgcn_cvt_pk_f32_fp8(vv[b].y, false);
        a8[4] = fmaf(wk[b], p[0], a8[4]); a8[5] = fmaf(wk[b], p[1], a8[5]);
        p = __builtin_amdgcn_cvt_pk_f32_fp8(vv[b].y, true);
        a8[6] = fmaf(wk[b], p[0], a8[6]); a8[7] = fmaf(wk[b], p[1], a8[7]);
    }
    #pragma unroll
    for (int i = 0; i < 8; ++i) {
        a8[i] += __shfl_xor(a8[i], 16);
        a8[i] += __shfl_xor(a8[i], 32);
    }
    if (lane < 16) {
        unsigned lo = pk4fp8(8.f*a8[0], 8.f*a8[1], 8.f*a8[2], 8.f*a8[3]);
        unsigned hi = pk4fp8(8.f*a8[4], 8.f*a8[5], 8.f*a8[6], 8.f*a8[7]);
        *(uint2*)((unsigned char*)qt + (size_t)n*256 + c*8) = make_uint2(lo, hi);
    }
}

// ---------------- K3: fused tail — R18 + kb-loop unroll 1 (I-cache probe) --
// Single variable vs R18: #pragma unroll 1 on the FFN kb loop. If the ~95us
// attractor is instruction-fetch bound (hot path ~15KB unrolled), shrinking
// the loop body 4x should show a large win; if neutral, I-cache is excluded.
__global__ __launch_bounds__(512, 2) void k_tail(
        const unsigned char* __restrict__ ctx8, const float* __restrict__ ob,
        const ushort* __restrict__ xb,
        const float* __restrict__ g1, const float* __restrict__ be1,
        const unsigned char* __restrict__ wcat8, const float* __restrict__ b1,
        const float* __restrict__ b2,
        const float* __restrict__ g2, const float* __restrict__ be2,
        float* __restrict__ out, int N) {
    __shared__ __align__(16) unsigned char smem[147456];
    const int tid = threadIdx.x;
    const int wave = tid >> 6, lane = tid & 63;
    const int l16 = lane & 15, l4 = lane >> 4;

    // one-time weight load: 147456B / 512thr = 18 x uint4 per thread
    {
        const uint4* src = (const uint4*)wcat8;
        #pragma unroll
        for (int b = 0; b < 3; ++b) {
            uint4 v[6];
            #pragma unroll
            for (int j = 0; j < 6; ++j) v[j] = src[(b*6 + j)*512 + tid];
            #pragma unroll
            for (int j = 0; j < 6; ++j)
                *(uint4*)(smem + ((size_t)(b*6 + j)*512 + tid)*16) = v[j];
        }
    }
    __syncthreads();

    const int ntiles = (N + 31) >> 5;
    const int nwv = gridDim.x * 8;
    for (int t = blockIdx.x * 8 + wave; t < ntiles; t += nwv) {
        int row[2], rc[2];
        row[0] = t*32 + l16;      rc[0] = row[0] < N ? row[0] : N - 1;
        row[1] = t*32 + 16 + l16; rc[1] = row[1] < N ? row[1] : N - 1;

        // ---- out-proj: A = wob8 (LDS), B = ctx8 (global fp8) ----
        f32x4 acc[2][8];
        #pragma unroll
        for (int mt = 0; mt < 2; ++mt)
            #pragma unroll
            for (int nt = 0; nt < 8; ++nt) acc[mt][nt] = (f32x4){0.f,0.f,0.f,0.f};
        {
            long cf[2][4];
            #pragma unroll
            for (int mt = 0; mt < 2; ++mt)
                #pragma unroll
                for (int c = 0; c < 4; ++c)
                    cf[mt][c] = *(const long*)(ctx8 + (size_t)rc[mt]*256 + c*32 + l4*8);
            #pragma unroll
            for (int nt = 0; nt < 8; ++nt) {
                #pragma unroll
                for (int c = 0; c < 4; ++c) {
                    long wf = *(const long*)(smem + (nt*16 + l16)*128 + (((c*4 + l4) ^ l16) << 3));
                    acc[0][nt] = __builtin_amdgcn_mfma_f32_16x16x32_fp8_fp8(wf, cf[0][c], acc[0][nt], 0, 0, 0);
                    acc[1][nt] = __builtin_amdgcn_mfma_f32_16x16x32_fp8_fp8(wf, cf[1][c], acc[1][nt], 0, 0, 0);
                }
            }
        }

        // ---- bias + x residual + LN1 ----
        float sum0 = 0.f, sq0 = 0.f, sum1 = 0.f, sq1 = 0.f;
        #pragma unroll
        for (int nt = 0; nt < 8; ++nt) {
            f32x4 obv = *(const f32x4*)(ob + nt*16 + l4*4);
            uint2 xr0 = *(const uint2*)(xb + (size_t)rc[0]*128 + nt*16 + l4*4);
            uint2 xr1 = *(const uint2*)(xb + (size_t)rc[1]*128 + nt*16 + l4*4);
            acc[0][nt][0] = acc[0][nt][0]*(1.f/128.f) + obv[0] + bflo(xr0.x);
            acc[0][nt][1] = acc[0][nt][1]*(1.f/128.f) + obv[1] + bfhi(xr0.x);
            acc[0][nt][2] = acc[0][nt][2]*(1.f/128.f) + obv[2] + bflo(xr0.y);
            acc[0][nt][3] = acc[0][nt][3]*(1.f/128.f) + obv[3] + bfhi(xr0.y);
            acc[1][nt][0] = acc[1][nt][0]*(1.f/128.f) + obv[0] + bflo(xr1.x);
            acc[1][nt][1] = acc[1][nt][1]*(1.f/128.f) + obv[1] + bfhi(xr1.x);
            acc[1][nt][2] = acc[1][nt][2]*(1.f/128.f) + obv[2] + bflo(xr1.y);
            acc[1][nt][3] = acc[1][nt][3]*(1.f/128.f) + obv[3] + bfhi(xr1.y);
            #pragma unroll
            for (int r = 0; r < 4; ++r) {
                sum0 += acc[0][nt][r]; sq0 += acc[0][nt][r]*acc[0][nt][r];
                sum1 += acc[1][nt][r]; sq1 += acc[1][nt][r]*acc[1][nt][r];
            }
        }
        sum0 += __shfl_xor(sum0, 16); sum0 += __shfl_xor(sum0, 32);
        sq0  += __shfl_xor(sq0, 16);  sq0  += __shfl_xor(sq0, 32);
        sum1 += __shfl_xor(sum1, 16); sum1 += __shfl_xor(sum1, 32);
        sq1  += __shfl_xor(sq1, 16);  sq1  += __shfl_xor(sq1, 32);
        float mean[2], rstd[2];
        mean[0] = sum0 * (1.f/128.f);
        rstd[0] = rsqrtf(sq0*(1.f/128.f) - mean[0]*mean[0] + EPS);
        mean[1] = sum1 * (1.f/128.f);
        rstd[1] = rsqrtf(sq1*(1.f/128.f) - mean[1]*mean[1] + EPS);

        // y -> bf16 (residual) + fp8 (MFMA B-operand)
        short8 yf16[2][4];
        long   yf8[2][4];
        #pragma unroll
        for (int mt = 0; mt < 2; ++mt) {
            #pragma unroll
            for (int c = 0; c < 4; ++c) {
                float yv[8];
                #pragma unroll
                for (int half = 0; half < 2; ++half) {
                    int nt = 2*c + half;
                    f32x4 gv = *(const f32x4*)(g1 + nt*16 + l4*4);
                    f32x4 bv = *(const f32x4*)(be1 + nt*16 + l4*4);
                    #pragma unroll
                    for (int r = 0; r < 4; ++r) {
                        float yn = (acc[mt][nt][r] - mean[mt]) * rstd[mt] * gv[r] + bv[r];
                        yv[half*4 + r] = yn;
                        yf16[mt][c][half*4 + r] = (short)f2bf(yn);
                    }
                }
                unsigned lo = pk4fp8(yv[0], yv[1], yv[2], yv[3]);
                unsigned hi = pk4fp8(yv[4], yv[5], yv[6], yv[7]);
                yf8[mt][c] = (long)(((unsigned long long)hi << 32) | lo);
            }
        }

        // ---- FFN: acc reused as acc2; kb loop NOT unrolled (I-cache probe) --
        f32x4 (&acc2)[2][8] = acc;
        #pragma unroll
        for (int mt = 0; mt < 2; ++mt)
            #pragma unroll
            for (int nt = 0; nt < 8; ++nt) acc2[mt][nt] = (f32x4){0.f,0.f,0.f,0.f};
        #pragma unroll 1
        for (int kb = 0; kb < 16; ++kb) {
            const unsigned char* w1b = smem + 16384 + kb*4096;
            long wA[4], wB[4];
            #pragma unroll
            for (int c = 0; c < 4; ++c) {
                int so = ((c*4 + l4) ^ l16) << 3;
                wA[c] = *(const long*)(w1b + l16*128 + so);
                wB[c] = *(const long*)(w1b + (16 + l16)*128 + so);
            }
            f32x4 hA[2] = {{0.f,0.f,0.f,0.f},{0.f,0.f,0.f,0.f}};
            f32x4 hB[2] = {{0.f,0.f,0.f,0.f},{0.f,0.f,0.f,0.f}};
            #pragma unroll
            for (int c = 0; c < 4; ++c)
                #pragma unroll
                for (int mt = 0; mt < 2; ++mt) {
                    hA[mt] = __builtin_amdgcn_mfma_f32_16x16x32_fp8_fp8(wA[c], yf8[mt][c], hA[mt], 0, 0, 0);
                    hB[mt] = __builtin_amdgcn_mfma_f32_16x16x32_fp8_fp8(wB[c], yf8[mt][c], hB[mt], 0, 0, 0);
                }
            f32x4 bA = *(const f32x4*)(b1 + kb*32 + l4*4);
            f32x4 bB = *(const f32x4*)(b1 + kb*32 + 16 + l4*4);
            long hf8[2];
            #pragma unroll
            for (int mt = 0; mt < 2; ++mt) {
                float vA[4], vB[4];
                #pragma unroll
                for (int r = 0; r < 4; ++r) {
                    vA[r] = fmaxf(hA[mt][r]*0.0625f + bA[r], 0.f);
                    vB[r] = fmaxf(hB[mt][r]*0.0625f + bB[r], 0.f);
                }
                unsigned lo = pk4fp8(vA[0], vA[1], vA[2], vA[3]);
                unsigned hi = pk4fp8(vB[0], vB[1], vB[2], vB[3]);
                hf8[mt] = (long)(((unsigned long long)hi << 32) | lo);
            }
            const unsigned char* w2b = smem + 81920 + kb*4096 + l4*1024;
            #pragma unroll
            for (int nt = 0; nt < 8; ++nt) {
                long w2f = *(const long*)(w2b + (nt*16 + l16)*8);
                acc2[0][nt] = __builtin_amdgcn_mfma_f32_16x16x32_fp8_fp8(w2f, hf8[0], acc2[0][nt], 0, 0, 0);
                acc2[1][nt] = __builtin_amdgcn_mfma_f32_16x16x32_fp8_fp8(w2f, hf8[1], acc2[1][nt], 0, 0, 0);
            }
        }

        // ---- s = y + ff/16 + b2, LN2, store ----
        #pragma unroll
        for (int mt = 0; mt < 2; ++mt) {
            float sum2 = 0.f, sq2 = 0.f;
            #pragma unroll
            for (int nt = 0; nt < 8; ++nt) {
                f32x4 b2v = *(const f32x4*)(b2 + nt*16 + l4*4);
                #pragma unroll
                for (int r = 0; r < 4; ++r) {
                    float s = bf2f((ushort)yf16[mt][nt >> 1][(nt & 1)*4 + r])
                              + acc2[mt][nt][r]*0.0625f + b2v[r];
                    acc2[mt][nt][r] = s; sum2 += s; sq2 += s*s;
                }
            }
            sum2 += __shfl_xor(sum2, 16); sum2 += __shfl_xor(sum2, 32);
            sq2  += __shfl_xor(sq2, 16);  sq2  += __shfl_xor(sq2, 32);
            float mean2 = sum2 * (1.f/128.f);
            float rstd2 = rsqrtf(sq2*(1.f/128.f) - mean2*mean2 + EPS);
            if (row[mt] < N) {
                #pragma unroll
                for (int nt = 0; nt < 8; ++nt) {
                    f32x4 gv = *(const f32x4*)(g2 + nt*16 + l4*4);
                    f32x4 bv = *(const f32x4*)(be2 + nt*16 + l4*4);
                    f32x4 o;
                    #pragma unroll
                    for (int r = 0; r < 4; ++r)
                        o[r] = (acc2[mt][nt][r] - mean2) * rstd2 * gv[r] + bv[r];
                    *(f32x4*)(out + (size_t)row[mt]*128 + nt*16 + l4*4) = o;
                }
            }
        }
    }
}

extern "C" void kernel_launch(void* const* d_in, const int* in_sizes, int n_in,
                              void* d_out, int out_size, void* d_ws, size_t ws_size,
                              hipStream_t stream) {
    (void)n_in; (void)out_size; (void)ws_size;
    const float* x   = (const float*)d_in[0];
    const int*   smp = (const int*)  d_in[1];
    const float* ipw = (const float*)d_in[2];
    const float* ipb = (const float*)d_in[3];
    const float* ow  = (const float*)d_in[4];
    const float* ob  = (const float*)d_in[5];
    const float* w1  = (const float*)d_in[6];
    const float* b1  = (const float*)d_in[7];
    const float* w2  = (const float*)d_in[8];
    const float* b2  = (const float*)d_in[9];
    const float* g1  = (const float*)d_in[10];
    const float* be1 = (const float*)d_in[11];
    const float* g2  = (const float*)d_in[12];
    const float* be2 = (const float*)d_in[13];
    const int N = in_sizes[0] / 128;

    ushort* qt   = (ushort*)d_ws;                        // [N][128] bf16 q; ctx8 fp8 overlays
    unsigned char* kv8 = (unsigned char*)(qt + (size_t)N*128);   // [N][256] fp8 K|V
    ushort* wqb  = (ushort*)(kv8 + (size_t)N*256);       // 384*128 bf16
    unsigned char* wcat8 = (unsigned char*)(wqb + 49152);// 147456 B fp8 LDS image
    ushort* xb   = (ushort*)(wcat8 + 147456);            // [N][128] bf16 x
    float*  outp = (float*)d_out;

    k_prep <<<576,       256, 0, stream>>>(ipw, ow, w1, w2, wqb, wcat8);
    k_qkv  <<<(N+63)/64, 256, 0, stream>>>(x, wqb, ipb, qt, kv8, xb, N);
    k_attn <<<(N+3)/4,   256, 0, stream>>>(qt, kv8, smp, N);
    k_tail <<<256,       512, 0, stream>>>((const unsigned char*)qt, ob, xb, g1, be1,
                                           wcat8, b1, b2, g2, be2, outp, N);
}